// Round 1
// baseline (1773.802 us; speedup 1.0000x reference)
//
#include <hip/hip_runtime.h>
#include <hip/hip_bf16.h>

typedef __attribute__((ext_vector_type(8))) short short8;
typedef __attribute__((ext_vector_type(4))) float f32x4;

#define GEPS 1e-5f

__device__ __forceinline__ unsigned short f2bf(float f) {
    unsigned int u = __float_as_uint(f);
    u += 0x7fffu + ((u >> 16) & 1u);
    return (unsigned short)(u >> 16);
}
__device__ __forceinline__ float bf2f(unsigned short h) {
    return __uint_as_float(((unsigned int)h) << 16);
}
__device__ __forceinline__ float wred_sum(float v) {
    #pragma unroll
    for (int off = 32; off > 0; off >>= 1) v += __shfl_xor(v, off);
    return v;
}
__device__ __forceinline__ float wred_max(float v) {
    #pragma unroll
    for (int off = 32; off > 0; off >>= 1) v = fmaxf(v, __shfl_xor(v, off));
    return v;
}

// ---------------------------------------------------------------------------
// Stage A: depthwise 3x3 conv stride 8 pad 1 + bias + eval-BN  -> [32,512,7,7]
// grid (32*512, 3 paths), 256 thr. Only 21 of 56 rows are touched.
// ---------------------------------------------------------------------------
__global__ __launch_bounds__(256) void k_dwconv_bn(
    const float* __restrict__ qi, const float* __restrict__ ki, const float* __restrict__ vi,
    const float* __restrict__ qw, const float* __restrict__ qb, const float* __restrict__ qg, const float* __restrict__ qbb,
    const float* __restrict__ kw, const float* __restrict__ kb, const float* __restrict__ kg, const float* __restrict__ kbb,
    const float* __restrict__ vw, const float* __restrict__ vb, const float* __restrict__ vg, const float* __restrict__ vbb,
    float* __restrict__ oq, float* __restrict__ ok, float* __restrict__ ov)
{
    int path = blockIdx.y;
    const float* in = path == 0 ? qi : (path == 1 ? ki : vi);
    const float* w  = path == 0 ? qw : (path == 1 ? kw : vw);
    const float* bi = path == 0 ? qb : (path == 1 ? kb : vb);
    const float* g  = path == 0 ? qg : (path == 1 ? kg : vg);
    const float* bb = path == 0 ? qbb: (path == 1 ? kbb: vbb);
    float* out = path == 0 ? oq : (path == 1 ? ok : ov);

    int bc = blockIdx.x;            // b*512 + c
    int c  = bc & 511;
    __shared__ float patch[21 * 56];
    const float* src = in + (size_t)bc * 3136;
    for (int idx = threadIdx.x; idx < 21 * 56; idx += 256) {
        int j = idx / 56, col = idx - j * 56;
        int ir = 8 * (j / 3) + (j % 3) - 1;          // -1,0,1,7,8,9,...,47,48,49
        patch[idx] = (ir >= 0) ? src[ir * 56 + col] : 0.f;
    }
    __syncthreads();
    int t = threadIdx.x;
    if (t < 49) {
        int oh = t / 7, ow = t - oh * 7;
        float acc = 0.f;
        #pragma unroll
        for (int kh = 0; kh < 3; kh++) {
            #pragma unroll
            for (int kw2 = 0; kw2 < 3; kw2++) {
                int col = ow * 8 + kw2 - 1;
                if (col >= 0)
                    acc += patch[(oh * 3 + kh) * 56 + col] * w[c * 9 + kh * 3 + kw2];
            }
        }
        float scale = g[c] * rsqrtf(1.f + GEPS);
        out[bc * 49 + t] = (acc + bi[c]) * scale + bb[c];
    }
}

// ---------------------------------------------------------------------------
// Stage B: 1x1 conv (512x512) + GroupNorm(32) + path-specific L2 normalize.
// grid (32*8 heads, 3 paths), 256 thr. One block = one (b, head): 64 out ch
// = 4 full GN groups; q: column-normalize over d; k: row-normalize over n.
// ---------------------------------------------------------------------------
__global__ __launch_bounds__(256) void k_pw_gn(
    const float* __restrict__ q4, const float* __restrict__ k4, const float* __restrict__ v4,
    const float* __restrict__ wq, const float* __restrict__ wk, const float* __restrict__ wv,
    const float* __restrict__ gqg, const float* __restrict__ gqb,
    const float* __restrict__ gkg, const float* __restrict__ gkb,
    const float* __restrict__ gvg, const float* __restrict__ gvb,
    float* __restrict__ qnf, float* __restrict__ knf, float* __restrict__ vf)
{
    int path = blockIdx.y;
    const float* in = path == 0 ? q4 : (path == 1 ? k4 : v4);
    const float* W  = path == 0 ? wq : (path == 1 ? wk : wv);
    const float* gg = path == 0 ? gqg : (path == 1 ? gkg : gvg);
    const float* gb = path == 0 ? gqb : (path == 1 ? gkb : gvb);
    float* out = path == 0 ? qnf : (path == 1 ? knf : vf);

    int b    = blockIdx.x >> 3;
    int head = blockIdx.x & 7;
    int t = threadIdx.x;

    __shared__ float chunk[128 * 52];   // [ci][p], p padded to 52 (>=49, zeros)
    __shared__ float tile[64 * 50];     // [o_local][p]
    __shared__ float red[8];            // 4 means, 4 rstds
    __shared__ float cs[64];            // col/row L2 scales

    bool active = (t < 208);
    int to = t / 13, tp = t - to * 13;  // 16 x 13 thread tiles of 4x4
    int o_base = to * 4, p_base = tp * 4;

    float acc[4][4];
    #pragma unroll
    for (int i = 0; i < 4; i++)
        #pragma unroll
        for (int j = 0; j < 4; j++) acc[i][j] = 0.f;

    const float* inb = in + b * 512 * 49;
    for (int cc = 0; cc < 4; cc++) {
        for (int idx = t; idx < 128 * 52; idx += 256) {
            int ci = idx / 52, p = idx - ci * 52;
            chunk[idx] = (p < 49) ? inb[cc * 6272 + ci * 49 + p] : 0.f;
        }
        __syncthreads();
        if (active) {
            const float* w0 = W + (head * 64 + o_base) * 512 + cc * 128;
            for (int ci = 0; ci < 128; ci++) {
                float wr[4], xr[4];
                #pragma unroll
                for (int i = 0; i < 4; i++) wr[i] = w0[i * 512 + ci];
                #pragma unroll
                for (int j = 0; j < 4; j++) xr[j] = chunk[ci * 52 + p_base + j];
                #pragma unroll
                for (int i = 0; i < 4; i++)
                    #pragma unroll
                    for (int j = 0; j < 4; j++) acc[i][j] += wr[i] * xr[j];
            }
        }
        __syncthreads();
    }
    if (active) {
        #pragma unroll
        for (int i = 0; i < 4; i++)
            #pragma unroll
            for (int j = 0; j < 4; j++) {
                int p = p_base + j;
                if (p < 49) tile[(o_base + i) * 50 + p] = acc[i][j];
            }
    }
    __syncthreads();

    // GroupNorm stats: wave w handles group w (16 ch x 49 px)
    int wv_ = t >> 6, lane = t & 63;
    {
        float s = 0.f, s2 = 0.f;
        for (int idx = lane; idx < 784; idx += 64) {
            int ol = wv_ * 16 + idx / 49, p = idx % 49;
            float x = tile[ol * 50 + p];
            s += x; s2 += x * x;
        }
        s = wred_sum(s); s2 = wred_sum(s2);
        if (lane == 0) {
            float m = s / 784.f;
            red[wv_] = m;
            red[4 + wv_] = rsqrtf(s2 / 784.f - m * m + GEPS);
        }
    }
    __syncthreads();
    for (int idx = t; idx < 3136; idx += 256) {
        int ol = idx / 49, p = idx - ol * 49;
        int gl = ol >> 4;
        int cch = head * 64 + ol;
        tile[ol * 50 + p] = (tile[ol * 50 + p] - red[gl]) * red[4 + gl] * gg[cch] + gb[cch];
    }
    __syncthreads();

    float* outb = out + (b * 512 + head * 64) * 49;
    if (path == 0) {                 // q: L2 over d (column within head)
        if (t < 49) {
            float s = 0.f;
            for (int ol = 0; ol < 64; ol++) { float x = tile[ol * 50 + t]; s += x * x; }
            cs[t] = 1.f / fmaxf(sqrtf(s), 1e-12f);
        }
        __syncthreads();
        for (int idx = t; idx < 3136; idx += 256) {
            int ol = idx / 49, p = idx - ol * 49;
            outb[ol * 49 + p] = tile[ol * 50 + p] * cs[p];
        }
    } else if (path == 1) {          // k: L2 over tokens (row)
        if (t < 64) {
            float s = 0.f;
            for (int p = 0; p < 49; p++) { float x = tile[t * 50 + p]; s += x * x; }
            cs[t] = 1.f / fmaxf(sqrtf(s), 1e-12f);
        }
        __syncthreads();
        for (int idx = t; idx < 3136; idx += 256) {
            int ol = idx / 49, p = idx - ol * 49;
            outb[ol * 49 + p] = tile[ol * 50 + p] * cs[ol];
        }
    } else {                         // v: plain
        for (int idx = t; idx < 3136; idx += 256) {
            int ol = idx / 49, p = idx - ol * 49;
            outb[ol * 49 + p] = tile[ol * 50 + p];
        }
    }
}

// ---------------------------------------------------------------------------
// Stage D: grouped 3x3 conv (groups=8) on vf + GroupNorm -> v_local
// grid (32*8), 256 thr. Block = (b, group of 64 ch) = 4 GN groups.
// ---------------------------------------------------------------------------
__global__ __launch_bounds__(256) void k_vlocal(
    const float* __restrict__ vf, const float* __restrict__ lw,
    const float* __restrict__ lg, const float* __restrict__ lb,
    float* __restrict__ vloc)
{
    int b = blockIdx.x >> 3;
    int grp = blockIdx.x & 7;
    int t = threadIdx.x;
    __shared__ float tin[64 * 49];
    __shared__ float tout[64 * 50];
    __shared__ float red[8];
    const float* inb = vf + (b * 512 + grp * 64) * 49;
    for (int idx = t; idx < 64 * 49; idx += 256) tin[idx] = inb[idx];
    __syncthreads();
    for (int i = 0; i < 13; i++) {
        int idx = t + i * 256;
        if (idx < 3136) {
            int ol = idx / 49, p = idx - ol * 49;
            int y = p / 7, x = p - y * 7;
            const float* wr = lw + (grp * 64 + ol) * 576;
            float a = 0.f;
            for (int ic = 0; ic < 64; ic++) {
                const float* tc = tin + ic * 49;
                const float* wc = wr + ic * 9;
                #pragma unroll
                for (int kh = 0; kh < 3; kh++) {
                    int yy = y + kh - 1;
                    if (yy < 0 || yy > 6) continue;
                    const float* trow = tc + yy * 7;
                    const float* wrow = wc + kh * 3;
                    #pragma unroll
                    for (int kw2 = 0; kw2 < 3; kw2++) {
                        int xx = x + kw2 - 1;
                        if (xx >= 0 && xx <= 6) a += trow[xx] * wrow[kw2];
                    }
                }
            }
            tout[ol * 50 + p] = a;
        }
    }
    __syncthreads();
    int wv_ = t >> 6, lane = t & 63;
    float s = 0.f, s2 = 0.f;
    for (int idx = lane; idx < 784; idx += 64) {
        int ol = wv_ * 16 + idx / 49, p = idx % 49;
        float x = tout[ol * 50 + p];
        s += x; s2 += x * x;
    }
    s = wred_sum(s); s2 = wred_sum(s2);
    if (lane == 0) {
        float m = s / 784.f;
        red[wv_] = m;
        red[4 + wv_] = rsqrtf(s2 / 784.f - m * m + GEPS);
    }
    __syncthreads();
    float* ob = vloc + (b * 512 + grp * 64) * 49;
    for (int idx = t; idx < 3136; idx += 256) {
        int ol = idx / 49, p = idx - ol * 49;
        int gl = ol >> 4; int cch = grp * 64 + ol;
        ob[ol * 49 + p] = (tout[ol * 50 + p] - red[gl]) * red[4 + gl] * lg[cch] + lb[cch];
    }
}

// ---------------------------------------------------------------------------
// Stage C: cosine attention + rel-pos bias + talking heads + softmax + PV.
// grid (49 tokens, 32 batch), 64 thr (1 wave). Writes M = attn_out + v_local.
// ---------------------------------------------------------------------------
__global__ __launch_bounds__(64) void k_attn(
    const float* __restrict__ qnf, const float* __restrict__ knf, const float* __restrict__ vf,
    const float* __restrict__ vloc,
    const float* __restrict__ th1, const float* __restrict__ th2,
    const float* __restrict__ lsc, const float* __restrict__ abias,
    const int* __restrict__ bidx,
    float* __restrict__ M)
{
    int n = blockIdx.x;
    int b = blockIdx.y;
    int t = threadIdx.x;
    __shared__ float qcol[512];
    __shared__ float sA[392], sB[392];
    __shared__ float sth1[64], sth2[64], sls[8];

    sth1[t] = th1[t]; sth2[t] = th2[t];
    if (t < 8) sls[t] = expf(fminf(lsc[t], 4.6051702f));   // clamp at ln(100)
    #pragma unroll
    for (int i = 0; i < 8; i++) qcol[t + i * 64] = qnf[(b * 512 + t + i * 64) * 49 + n];
    __syncthreads();

    for (int e = t; e < 392; e += 64) {                     // S = qn . kn * ls + bias
        int h = e / 49, m = e - h * 49;
        const float* kb = knf + (b * 512 + h * 64) * 49 + m;
        const float* qc = qcol + h * 64;
        float dot = 0.f;
        #pragma unroll 8
        for (int d = 0; d < 64; d++) dot += qc[d] * kb[d * 49];
        sA[e] = dot * sls[h] + abias[h * 49 + bidx[n * 49 + m]];
    }
    __syncthreads();
    for (int e = t; e < 392; e += 64) {                     // talking head 1
        int i = e / 49, m = e - i * 49;
        float v = 0.f;
        #pragma unroll
        for (int j = 0; j < 8; j++) v += sth1[i * 8 + j] * sA[j * 49 + m];
        sB[e] = v;
    }
    __syncthreads();
    #pragma unroll
    for (int i = 0; i < 8; i++) {                           // softmax over m
        float v = (t < 49) ? sB[i * 49 + t] : -3.4e38f;
        float mx = wred_max(v);
        float e_ = (t < 49) ? expf(v - mx) : 0.f;
        float ss = wred_sum(e_);
        if (t < 49) sB[i * 49 + t] = e_ / ss;
    }
    __syncthreads();
    for (int e = t; e < 392; e += 64) {                     // talking head 2
        int i = e / 49, m = e - i * 49;
        float v = 0.f;
        #pragma unroll
        for (int j = 0; j < 8; j++) v += sth2[i * 8 + j] * sB[j * 49 + m];
        sA[e] = v;
    }
    __syncthreads();
    #pragma unroll
    for (int i = 0; i < 8; i++) {                           // O = A @ v, + v_local
        int ch = t + i * 64;
        int h = ch >> 6;
        const float* vr = vf + (b * 512 + ch) * 49;
        const float* ar = sA + h * 49;
        float a = 0.f;
        for (int m = 0; m < 49; m++) a += ar[m] * vr[m];
        M[(b * 512 + ch) * 49 + n] = a + vloc[(b * 512 + ch) * 49 + n];
    }
}

// ---------------------------------------------------------------------------
// Convert out_w to bf16 in K-chunked layout: Ws[(c/32)][o][c%32]
// ---------------------------------------------------------------------------
__global__ __launch_bounds__(256) void k_wconv(const float* __restrict__ W,
                                               unsigned short* __restrict__ Ws)
{
    int idx = blockIdx.x * 256 + threadIdx.x;   // o*512 + c
    int o = idx >> 9, c = idx & 511;
    Ws[(c >> 5) * 16384 + o * 32 + (c & 31)] = f2bf(W[idx]);
}

// ---------------------------------------------------------------------------
// Stage E1: fused bilinear-upsample + hardswish + bf16 MFMA GEMM + GN stats.
// grid (56 dst rows, 32 b), 256 thr (4 waves). Block: y[512 o][56 px of row].
// ---------------------------------------------------------------------------
__global__ __launch_bounds__(256) void k_gemm_stats(
    const unsigned short* __restrict__ Ws,
    const float* __restrict__ M,
    unsigned short* __restrict__ Y,
    float* __restrict__ stats)
{
    int row = blockIdx.x;
    int b = blockIdx.y;
    int t = threadIdx.x;
    __shared__ __attribute__((aligned(16))) unsigned short lA[512 * 40]; // [o][32c] pad 40
    __shared__ __attribute__((aligned(16))) unsigned short lB[64 * 40];  // [px][32c] pad 40
    __shared__ int six0[64], six1[64];
    __shared__ float sfx[64];

    float srcy = row * 0.125f - 0.4375f;
    int iy0 = (int)floorf(srcy);
    float fy = srcy - (float)iy0;
    int y0 = min(max(iy0, 0), 6);
    int y1 = min(max(iy0 + 1, 0), 6);

    if (t < 64) {
        if (t < 56) {
            float sx = t * 0.125f - 0.4375f;
            int ix0 = (int)floorf(sx);
            sfx[t] = sx - (float)ix0;
            six0[t] = min(max(ix0, 0), 6);
            six1[t] = min(max(ix0 + 1, 0), 6);
        } else { sfx[t] = 0.f; six0[t] = 0; six1[t] = 0; }
    }
    __syncthreads();

    f32x4 acc[8][4];
    const f32x4 zv = {0.f, 0.f, 0.f, 0.f};
    #pragma unroll
    for (int i = 0; i < 8; i++)
        #pragma unroll
        for (int j = 0; j < 4; j++) acc[i][j] = zv;

    int wv_ = t >> 6, lane = t & 63, quad = lane >> 4, l15 = lane & 15;
    const float* Mb = M + b * 512 * 49;

    for (int kk = 0; kk < 16; kk++) {
        // ---- A staging: Ws chunk kk -> lA (512x32, padded rows)
        const unsigned short* wsrc = Ws + kk * 16384;
        #pragma unroll
        for (int it = 0; it < 8; it++) {
            int u = it * 256 + t;
            int o = u >> 2, seg = u & 3;
            uint4 val = *(const uint4*)(wsrc + u * 8);
            *(uint4*)&lA[o * 40 + seg * 8] = val;
        }
        // ---- B staging: act = hardswish(bilinear(M)) for 32 c x 64 px
        #pragma unroll
        for (int ip = 0; ip < 4; ip++) {
            int pair = ip * 256 + t;
            int px = pair >> 4, cp = pair & 15;
            int c = kk * 32 + cp * 2;
            float a0 = 0.f, a1 = 0.f;
            if (px < 56) {
                const float* m0 = Mb + c * 49;
                int i00 = y0 * 7 + six0[px], i01 = y0 * 7 + six1[px];
                int i10 = y1 * 7 + six0[px], i11 = y1 * 7 + six1[px];
                float fx = sfx[px];
                {
                    float r0 = m0[i00] + fx * (m0[i01] - m0[i00]);
                    float r1 = m0[i10] + fx * (m0[i11] - m0[i10]);
                    float x = r0 + fy * (r1 - r0);
                    a0 = x * fminf(fmaxf(x + 3.f, 0.f), 6.f) * (1.f / 6.f);
                }
                const float* m1 = m0 + 49;
                {
                    float r0 = m1[i00] + fx * (m1[i01] - m1[i00]);
                    float r1 = m1[i10] + fx * (m1[i11] - m1[i10]);
                    float x = r0 + fy * (r1 - r0);
                    a1 = x * fminf(fmaxf(x + 3.f, 0.f), 6.f) * (1.f / 6.f);
                }
            }
            unsigned int packed = (unsigned int)f2bf(a0) | ((unsigned int)f2bf(a1) << 16);
            *(unsigned int*)&lB[px * 40 + cp * 2] = packed;
        }
        __syncthreads();
        // ---- MFMA
        short8 bfr[4];
        #pragma unroll
        for (int nb = 0; nb < 4; nb++)
            bfr[nb] = *(const short8*)&lB[(nb * 16 + l15) * 40 + quad * 8];
        #pragma unroll
        for (int mb = 0; mb < 8; mb++) {
            short8 af = *(const short8*)&lA[(wv_ * 128 + mb * 16 + l15) * 40 + quad * 8];
            #pragma unroll
            for (int nb = 0; nb < 4; nb++)
                acc[mb][nb] = __builtin_amdgcn_mfma_f32_16x16x32_bf16(af, bfr[nb], acc[mb][nb], 0, 0, 0);
        }
        __syncthreads();
    }

    // ---- GN partial stats (group = 16 consecutive o = one m-block)
    #pragma unroll
    for (int mb = 0; mb < 8; mb++) {
        float s = 0.f, s2 = 0.f;
        #pragma unroll
        for (int nb = 0; nb < 4; nb++) {
            int px = nb * 16 + l15;
            if (px < 56) {
                #pragma unroll
                for (int i = 0; i < 4; i++) { float v = acc[mb][nb][i]; s += v; s2 += v * v; }
            }
        }
        s = wred_sum(s); s2 = wred_sum(s2);
        if (lane == 0) {
            int g = wv_ * 8 + mb;
            atomicAdd(&stats[(b * 32 + g) * 2], s);
            atomicAdd(&stats[(b * 32 + g) * 2 + 1], s2);
        }
    }
    // ---- store y (bf16), layout [b][row][o][56]
    unsigned short* yb = Y + (size_t)((b * 56 + row) * 512) * 56;
    #pragma unroll
    for (int mb = 0; mb < 8; mb++) {
        #pragma unroll
        for (int nb = 0; nb < 4; nb++) {
            int px = nb * 16 + l15;
            if (px < 56) {
                #pragma unroll
                for (int i = 0; i < 4; i++) {
                    int o = wv_ * 128 + mb * 16 + quad * 4 + i;
                    yb[o * 56 + px] = f2bf(acc[mb][nb][i]);
                }
            }
        }
    }
}

// ---------------------------------------------------------------------------
// Stage E1.5: finalize GN stats -> mean, rstd per (b, group)
// ---------------------------------------------------------------------------
__global__ __launch_bounds__(1024) void k_finstats(const float* __restrict__ stats,
                                                   float* __restrict__ mr)
{
    int t = threadIdx.x;  // 1024 = 32 b * 32 g
    float s = stats[t * 2], s2 = stats[t * 2 + 1];
    float m = s * (1.f / 50176.f);
    float var = s2 * (1.f / 50176.f) - m * m;
    mr[t * 2] = m;
    mr[t * 2 + 1] = rsqrtf(var + GEPS);
}

// ---------------------------------------------------------------------------
// Stage E2: normalize y, apply out_g/out_b, write fp32 output [32,512,56,56]
// grid (56 rows, 32 b), 256 thr.
// ---------------------------------------------------------------------------
__global__ __launch_bounds__(256) void k_norm_out(
    const unsigned short* __restrict__ Y, const float* __restrict__ mr,
    const float* __restrict__ og, const float* __restrict__ ob,
    float* __restrict__ out)
{
    int row = blockIdx.x, b = blockIdx.y;
    int t = threadIdx.x;
    const unsigned short* yb = Y + (size_t)((b * 56 + row) * 512) * 56;
    for (int idx2 = t; idx2 < 512 * 28; idx2 += 256) {
        int o = idx2 / 28, pp = (idx2 - o * 28) * 2;
        unsigned int u = *(const unsigned int*)(yb + o * 56 + pp);
        float v0 = bf2f((unsigned short)(u & 0xffffu));
        float v1 = bf2f((unsigned short)(u >> 16));
        int g = o >> 4;
        float m = mr[(b * 32 + g) * 2], r = mr[(b * 32 + g) * 2 + 1];
        float sc = og[o] * r;
        float sh = ob[o] - m * sc;
        float2 res = make_float2(v0 * sc + sh, v1 * sc + sh);
        *(float2*)(out + (size_t)((b * 512 + o) * 56 + row) * 56 + pp) = res;
    }
}

// ---------------------------------------------------------------------------
extern "C" void kernel_launch(void* const* d_in, const int* in_sizes, int n_in,
                              void* d_out, int out_size, void* d_ws, size_t ws_size,
                              hipStream_t stream)
{
    const float* query = (const float*)d_in[0];
    const float* key   = (const float*)d_in[1];
    const float* value = (const float*)d_in[2];
    const float* qs_w = (const float*)d_in[3];
    const float* qs_b = (const float*)d_in[4];
    const float* qs_g = (const float*)d_in[5];
    const float* qs_bb = (const float*)d_in[6];
    const float* ks_w = (const float*)d_in[7];
    const float* ks_b = (const float*)d_in[8];
    const float* ks_g = (const float*)d_in[9];
    const float* ks_bb = (const float*)d_in[10];
    const float* vs_w = (const float*)d_in[11];
    const float* vs_b = (const float*)d_in[12];
    const float* vs_g = (const float*)d_in[13];
    const float* vs_bb = (const float*)d_in[14];
    const float* wq = (const float*)d_in[15];
    const float* gq_g = (const float*)d_in[16];
    const float* gq_b = (const float*)d_in[17];
    const float* wk = (const float*)d_in[18];
    const float* gk_g = (const float*)d_in[19];
    const float* gk_b = (const float*)d_in[20];
    const float* wv = (const float*)d_in[21];
    const float* gv_g = (const float*)d_in[22];
    const float* gv_b = (const float*)d_in[23];
    const float* loc_w = (const float*)d_in[24];
    const float* loc_g = (const float*)d_in[25];
    const float* loc_b = (const float*)d_in[26];
    const float* th1_w = (const float*)d_in[27];
    const float* th2_w = (const float*)d_in[28];
    const float* logit_scale = (const float*)d_in[29];
    const float* attn_bias = (const float*)d_in[30];
    const int*   bias_idx = (const int*)d_in[31];
    const float* out_w = (const float*)d_in[32];
    const float* out_g = (const float*)d_in[33];
    const float* out_b = (const float*)d_in[34];

    char* ws = (char*)d_ws;
    size_t off = 0;
    unsigned short* Y = (unsigned short*)(ws + off); off += 102760448ULL;  // [32][56][512][56] bf16
    float* q4   = (float*)(ws + off); off += 3211264;
    float* k4   = (float*)(ws + off); off += 3211264;
    float* v4   = (float*)(ws + off); off += 3211264;
    float* qnf  = (float*)(ws + off); off += 3211264;
    float* knf  = (float*)(ws + off); off += 3211264;
    float* vf   = (float*)(ws + off); off += 3211264;
    float* Msm  = (float*)(ws + off); off += 3211264;
    float* vloc = (float*)(ws + off); off += 3211264;
    unsigned short* Wst = (unsigned short*)(ws + off); off += 524288;
    float* stats = (float*)(ws + off); off += 8192;
    float* mr    = (float*)(ws + off); off += 8192;

    hipMemsetAsync(stats, 0, 8192, stream);

    k_dwconv_bn<<<dim3(16384, 3), 256, 0, stream>>>(
        query, key, value,
        qs_w, qs_b, qs_g, qs_bb,
        ks_w, ks_b, ks_g, ks_bb,
        vs_w, vs_b, vs_g, vs_bb,
        q4, k4, v4);

    k_pw_gn<<<dim3(256, 3), 256, 0, stream>>>(
        q4, k4, v4, wq, wk, wv,
        gq_g, gq_b, gk_g, gk_b, gv_g, gv_b,
        qnf, knf, vf);

    k_vlocal<<<dim3(256), 256, 0, stream>>>(vf, loc_w, loc_g, loc_b, vloc);

    k_attn<<<dim3(49, 32), 64, 0, stream>>>(
        qnf, knf, vf, vloc, th1_w, th2_w, logit_scale, attn_bias, bias_idx, Msm);

    k_wconv<<<dim3(1024), 256, 0, stream>>>(out_w, Wst);

    k_gemm_stats<<<dim3(56, 32), 256, 0, stream>>>(Wst, Msm, Y, stats);

    k_finstats<<<dim3(1), 1024, 0, stream>>>(stats, mr);

    k_norm_out<<<dim3(56, 32), 256, 0, stream>>>(Y, mr, out_g, out_b, (float*)d_out);
}

// Round 2
// 1164.704 us; speedup vs baseline: 1.5230x; 1.5230x over previous
//
#include <hip/hip_runtime.h>
#include <hip/hip_bf16.h>

typedef __attribute__((ext_vector_type(8))) short short8;
typedef __attribute__((ext_vector_type(4))) float f32x4;

#define GEPS 1e-5f

__device__ __forceinline__ unsigned short f2bf(float f) {
    unsigned int u = __float_as_uint(f);
    u += 0x7fffu + ((u >> 16) & 1u);
    return (unsigned short)(u >> 16);
}
__device__ __forceinline__ float bf2f(unsigned short h) {
    return __uint_as_float(((unsigned int)h) << 16);
}
__device__ __forceinline__ float wred_sum(float v) {
    #pragma unroll
    for (int off = 32; off > 0; off >>= 1) v += __shfl_xor(v, off);
    return v;
}
__device__ __forceinline__ float wred_max(float v) {
    #pragma unroll
    for (int off = 32; off > 0; off >>= 1) v = fmaxf(v, __shfl_xor(v, off));
    return v;
}

// ---------------------------------------------------------------------------
// Stage A: depthwise 3x3 conv stride 8 pad 1 + bias + eval-BN  -> [32,512,7,7]
// grid (32*512, 3 paths), 256 thr. Only 21 of 56 rows are touched.
// ---------------------------------------------------------------------------
__global__ __launch_bounds__(256) void k_dwconv_bn(
    const float* __restrict__ qi, const float* __restrict__ ki, const float* __restrict__ vi,
    const float* __restrict__ qw, const float* __restrict__ qb, const float* __restrict__ qg, const float* __restrict__ qbb,
    const float* __restrict__ kw, const float* __restrict__ kb, const float* __restrict__ kg, const float* __restrict__ kbb,
    const float* __restrict__ vw, const float* __restrict__ vb, const float* __restrict__ vg, const float* __restrict__ vbb,
    float* __restrict__ oq, float* __restrict__ ok, float* __restrict__ ov)
{
    int path = blockIdx.y;
    const float* in = path == 0 ? qi : (path == 1 ? ki : vi);
    const float* w  = path == 0 ? qw : (path == 1 ? kw : vw);
    const float* bi = path == 0 ? qb : (path == 1 ? kb : vb);
    const float* g  = path == 0 ? qg : (path == 1 ? kg : vg);
    const float* bb = path == 0 ? qbb: (path == 1 ? kbb: vbb);
    float* out = path == 0 ? oq : (path == 1 ? ok : ov);

    int bc = blockIdx.x;            // b*512 + c
    int c  = bc & 511;
    __shared__ float patch[21 * 56];
    const float* src = in + (size_t)bc * 3136;
    for (int idx = threadIdx.x; idx < 21 * 56; idx += 256) {
        int j = idx / 56, col = idx - j * 56;
        int ir = 8 * (j / 3) + (j % 3) - 1;          // -1,0,1,7,8,9,...,47,48,49
        patch[idx] = (ir >= 0) ? src[ir * 56 + col] : 0.f;
    }
    __syncthreads();
    int t = threadIdx.x;
    if (t < 49) {
        int oh = t / 7, ow = t - oh * 7;
        float acc = 0.f;
        #pragma unroll
        for (int kh = 0; kh < 3; kh++) {
            #pragma unroll
            for (int kw2 = 0; kw2 < 3; kw2++) {
                int col = ow * 8 + kw2 - 1;
                if (col >= 0)
                    acc += patch[(oh * 3 + kh) * 56 + col] * w[c * 9 + kh * 3 + kw2];
            }
        }
        float scale = g[c] * rsqrtf(1.f + GEPS);
        out[bc * 49 + t] = (acc + bi[c]) * scale + bb[c];
    }
}

// ---------------------------------------------------------------------------
// Stage B: 1x1 conv (512x512) + GroupNorm(32) + path-specific L2 normalize.
// grid (32*8 heads, 3 paths), 256 thr.
// ---------------------------------------------------------------------------
__global__ __launch_bounds__(256) void k_pw_gn(
    const float* __restrict__ q4, const float* __restrict__ k4, const float* __restrict__ v4,
    const float* __restrict__ wq, const float* __restrict__ wk, const float* __restrict__ wv,
    const float* __restrict__ gqg, const float* __restrict__ gqb,
    const float* __restrict__ gkg, const float* __restrict__ gkb,
    const float* __restrict__ gvg, const float* __restrict__ gvb,
    float* __restrict__ qnf, float* __restrict__ knf, float* __restrict__ vf)
{
    int path = blockIdx.y;
    const float* in = path == 0 ? q4 : (path == 1 ? k4 : v4);
    const float* W  = path == 0 ? wq : (path == 1 ? wk : wv);
    const float* gg = path == 0 ? gqg : (path == 1 ? gkg : gvg);
    const float* gb = path == 0 ? gqb : (path == 1 ? gkb : gvb);
    float* out = path == 0 ? qnf : (path == 1 ? knf : vf);

    int b    = blockIdx.x >> 3;
    int head = blockIdx.x & 7;
    int t = threadIdx.x;

    __shared__ float chunk[128 * 52];   // [ci][p], p padded to 52 (>=49, zeros)
    __shared__ float tile[64 * 50];     // [o_local][p]
    __shared__ float red[8];            // 4 means, 4 rstds
    __shared__ float cs[64];            // col/row L2 scales

    bool active = (t < 208);
    int to = t / 13, tp = t - to * 13;  // 16 x 13 thread tiles of 4x4
    int o_base = to * 4, p_base = tp * 4;

    float acc[4][4];
    #pragma unroll
    for (int i = 0; i < 4; i++)
        #pragma unroll
        for (int j = 0; j < 4; j++) acc[i][j] = 0.f;

    const float* inb = in + b * 512 * 49;
    for (int cc = 0; cc < 4; cc++) {
        for (int idx = t; idx < 128 * 52; idx += 256) {
            int ci = idx / 52, p = idx - ci * 52;
            chunk[idx] = (p < 49) ? inb[cc * 6272 + ci * 49 + p] : 0.f;
        }
        __syncthreads();
        if (active) {
            const float* w0 = W + (head * 64 + o_base) * 512 + cc * 128;
            for (int ci = 0; ci < 128; ci++) {
                float wr[4], xr[4];
                #pragma unroll
                for (int i = 0; i < 4; i++) wr[i] = w0[i * 512 + ci];
                #pragma unroll
                for (int j = 0; j < 4; j++) xr[j] = chunk[ci * 52 + p_base + j];
                #pragma unroll
                for (int i = 0; i < 4; i++)
                    #pragma unroll
                    for (int j = 0; j < 4; j++) acc[i][j] += wr[i] * xr[j];
            }
        }
        __syncthreads();
    }
    if (active) {
        #pragma unroll
        for (int i = 0; i < 4; i++)
            #pragma unroll
            for (int j = 0; j < 4; j++) {
                int p = p_base + j;
                if (p < 49) tile[(o_base + i) * 50 + p] = acc[i][j];
            }
    }
    __syncthreads();

    // GroupNorm stats: wave w handles group w (16 ch x 49 px)
    int wv_ = t >> 6, lane = t & 63;
    {
        float s = 0.f, s2 = 0.f;
        for (int idx = lane; idx < 784; idx += 64) {
            int ol = wv_ * 16 + idx / 49, p = idx % 49;
            float x = tile[ol * 50 + p];
            s += x; s2 += x * x;
        }
        s = wred_sum(s); s2 = wred_sum(s2);
        if (lane == 0) {
            float m = s / 784.f;
            red[wv_] = m;
            red[4 + wv_] = rsqrtf(s2 / 784.f - m * m + GEPS);
        }
    }
    __syncthreads();
    for (int idx = t; idx < 3136; idx += 256) {
        int ol = idx / 49, p = idx - ol * 49;
        int gl = ol >> 4;
        int cch = head * 64 + ol;
        tile[ol * 50 + p] = (tile[ol * 50 + p] - red[gl]) * red[4 + gl] * gg[cch] + gb[cch];
    }
    __syncthreads();

    float* outb = out + (b * 512 + head * 64) * 49;
    if (path == 0) {                 // q: L2 over d (column within head)
        if (t < 49) {
            float s = 0.f;
            for (int ol = 0; ol < 64; ol++) { float x = tile[ol * 50 + t]; s += x * x; }
            cs[t] = 1.f / fmaxf(sqrtf(s), 1e-12f);
        }
        __syncthreads();
        for (int idx = t; idx < 3136; idx += 256) {
            int ol = idx / 49, p = idx - ol * 49;
            outb[ol * 49 + p] = tile[ol * 50 + p] * cs[p];
        }
    } else if (path == 1) {          // k: L2 over tokens (row)
        if (t < 64) {
            float s = 0.f;
            for (int p = 0; p < 49; p++) { float x = tile[t * 50 + p]; s += x * x; }
            cs[t] = 1.f / fmaxf(sqrtf(s), 1e-12f);
        }
        __syncthreads();
        for (int idx = t; idx < 3136; idx += 256) {
            int ol = idx / 49, p = idx - ol * 49;
            outb[ol * 49 + p] = tile[ol * 50 + p] * cs[ol];
        }
    } else {                         // v: plain
        for (int idx = t; idx < 3136; idx += 256) {
            int ol = idx / 49, p = idx - ol * 49;
            outb[ol * 49 + p] = tile[ol * 50 + p];
        }
    }
}

// ---------------------------------------------------------------------------
// Stage D (v2): grouped 3x3 conv (groups=8) + GroupNorm as register-blocked
// implicit GEMM. Block = (b, group): M=64 o, N=49 px, K=576 (64 ic x 9 taps).
// LDS: Wt[144][64] (transposed weights, per 16-ic chunk), Xc[144][64] im2col.
// Thread (to,tp) owns 4o x 4px tile: per K-step 2 x ds_read_b128 + 16 FMA.
// Wave w == GN group w (o 16w..16w+15): stats via wave reduction, no LDS.
// ---------------------------------------------------------------------------
__global__ __launch_bounds__(256) void k_vlocal(
    const float* __restrict__ vf, const float* __restrict__ lw,
    const float* __restrict__ lg, const float* __restrict__ lb,
    float* __restrict__ vloc)
{
    int b = blockIdx.x >> 3;
    int grp = blockIdx.x & 7;
    int t = threadIdx.x;
    __shared__ __attribute__((aligned(16))) float Wt[144 * 64];  // [k][o]
    __shared__ __attribute__((aligned(16))) float Xc[144 * 64];  // [k][px]

    const float* inb = vf + (b * 512 + grp * 64) * 49;
    const float* wgb = lw + (size_t)grp * 64 * 576;

    int to = t >> 4, tp = t & 15;
    int o_base = to * 4, px_base = tp * 4;

    // staging geometry: px = t&63 fixed per thread; k is wave-uniform per iter
    int spx = t & 63;
    int sy = spx / 7, sx = spx - sy * 7;
    int wvid = t >> 6;

    float acc[4][4];
    #pragma unroll
    for (int i = 0; i < 4; i++)
        #pragma unroll
        for (int j = 0; j < 4; j++) acc[i][j] = 0.f;

    for (int cc = 0; cc < 4; cc++) {
        // ---- Wt staging: quad q = i*256+t -> k=q>>4, o4=(q&15)*4.
        // 4 scalar global reads (L1/L2-hot), one aligned b128 LDS write.
        #pragma unroll
        for (int i = 0; i < 9; i++) {
            int q = i * 256 + t;
            int k = q >> 4, o4 = (q & 15) * 4;
            const float* wp = wgb + cc * 144 + k;
            f32x4 v;
            v[0] = wp[(o4 + 0) * 576];
            v[1] = wp[(o4 + 1) * 576];
            v[2] = wp[(o4 + 2) * 576];
            v[3] = wp[(o4 + 3) * 576];
            *(f32x4*)&Wt[k * 64 + o4] = v;
        }
        // ---- Xc im2col staging: k = i*4 + wave (uniform), px = lane geometry
        #pragma unroll
        for (int i = 0; i < 36; i++) {
            int k = i * 4 + wvid;
            int icl = k / 9, jj = k - icl * 9;
            int kh = jj / 3, kw2 = jj - kh * 3;
            int yy = sy + kh - 1, xx = sx + kw2 - 1;
            float v = 0.f;
            if (spx < 49 && yy >= 0 && yy <= 6 && xx >= 0 && xx <= 6)
                v = inb[(cc * 16 + icl) * 49 + yy * 7 + xx];
            Xc[k * 64 + spx] = v;
        }
        __syncthreads();
        // ---- compute: 144 K-steps, 16 FMA each
        #pragma unroll 4
        for (int k = 0; k < 144; k++) {
            f32x4 w4 = *(const f32x4*)&Wt[k * 64 + o_base];
            f32x4 x4 = *(const f32x4*)&Xc[k * 64 + px_base];
            #pragma unroll
            for (int i2 = 0; i2 < 4; i2++)
                #pragma unroll
                for (int j2 = 0; j2 < 4; j2++)
                    acc[i2][j2] += w4[i2] * x4[j2];
        }
        __syncthreads();
    }

    // ---- GN stats: wave w covers exactly group w (16 o x all px)
    float s = 0.f, s2 = 0.f;
    #pragma unroll
    for (int i = 0; i < 4; i++)
        #pragma unroll
        for (int j = 0; j < 4; j++) {
            float v = ((px_base + j) < 49) ? acc[i][j] : 0.f;
            s += v; s2 += v * v;
        }
    s = wred_sum(s); s2 = wred_sum(s2);
    float m = s * (1.f / 784.f);
    float r = rsqrtf(s2 * (1.f / 784.f) - m * m + GEPS);

    float* ob = vloc + (b * 512 + grp * 64) * 49;
    #pragma unroll
    for (int i = 0; i < 4; i++) {
        int o_l = o_base + i;
        int ch = grp * 64 + o_l;
        float sc = lg[ch] * r, sh = lb[ch] - m * sc;
        #pragma unroll
        for (int j = 0; j < 4; j++) {
            int px = px_base + j;
            if (px < 49) ob[o_l * 49 + px] = acc[i][j] * sc + sh;
        }
    }
}

// ---------------------------------------------------------------------------
// Stage C: cosine attention + rel-pos bias + talking heads + softmax + PV.
// grid (49 tokens, 32 batch), 64 thr (1 wave). Writes M = attn_out + v_local.
// ---------------------------------------------------------------------------
__global__ __launch_bounds__(64) void k_attn(
    const float* __restrict__ qnf, const float* __restrict__ knf, const float* __restrict__ vf,
    const float* __restrict__ vloc,
    const float* __restrict__ th1, const float* __restrict__ th2,
    const float* __restrict__ lsc, const float* __restrict__ abias,
    const int* __restrict__ bidx,
    float* __restrict__ M)
{
    int n = blockIdx.x;
    int b = blockIdx.y;
    int t = threadIdx.x;
    __shared__ float qcol[512];
    __shared__ float sA[392], sB[392];
    __shared__ float sth1[64], sth2[64], sls[8];

    sth1[t] = th1[t]; sth2[t] = th2[t];
    if (t < 8) sls[t] = expf(fminf(lsc[t], 4.6051702f));   // clamp at ln(100)
    #pragma unroll
    for (int i = 0; i < 8; i++) qcol[t + i * 64] = qnf[(b * 512 + t + i * 64) * 49 + n];
    __syncthreads();

    for (int e = t; e < 392; e += 64) {                     // S = qn . kn * ls + bias
        int h = e / 49, m = e - h * 49;
        const float* kb = knf + (b * 512 + h * 64) * 49 + m;
        const float* qc = qcol + h * 64;
        float dot = 0.f;
        #pragma unroll 8
        for (int d = 0; d < 64; d++) dot += qc[d] * kb[d * 49];
        sA[e] = dot * sls[h] + abias[h * 49 + bidx[n * 49 + m]];
    }
    __syncthreads();
    for (int e = t; e < 392; e += 64) {                     // talking head 1
        int i = e / 49, m = e - i * 49;
        float v = 0.f;
        #pragma unroll
        for (int j = 0; j < 8; j++) v += sth1[i * 8 + j] * sA[j * 49 + m];
        sB[e] = v;
    }
    __syncthreads();
    #pragma unroll
    for (int i = 0; i < 8; i++) {                           // softmax over m
        float v = (t < 49) ? sB[i * 49 + t] : -3.4e38f;
        float mx = wred_max(v);
        float e_ = (t < 49) ? expf(v - mx) : 0.f;
        float ss = wred_sum(e_);
        if (t < 49) sB[i * 49 + t] = e_ / ss;
    }
    __syncthreads();
    for (int e = t; e < 392; e += 64) {                     // talking head 2
        int i = e / 49, m = e - i * 49;
        float v = 0.f;
        #pragma unroll
        for (int j = 0; j < 8; j++) v += sth2[i * 8 + j] * sB[j * 49 + m];
        sA[e] = v;
    }
    __syncthreads();
    #pragma unroll
    for (int i = 0; i < 8; i++) {                           // O = A @ v, + v_local
        int ch = t + i * 64;
        int h = ch >> 6;
        const float* vr = vf + (b * 512 + ch) * 49;
        const float* ar = sA + h * 49;
        float a = 0.f;
        for (int m = 0; m < 49; m++) a += ar[m] * vr[m];
        M[(b * 512 + ch) * 49 + n] = a + vloc[(b * 512 + ch) * 49 + n];
    }
}

// ---------------------------------------------------------------------------
// Convert out_w to bf16 in K-chunked layout: Ws[(c/32)][o][c%32]
// ---------------------------------------------------------------------------
__global__ __launch_bounds__(256) void k_wconv(const float* __restrict__ W,
                                               unsigned short* __restrict__ Ws)
{
    int idx = blockIdx.x * 256 + threadIdx.x;   // o*512 + c
    int o = idx >> 9, c = idx & 511;
    Ws[(c >> 5) * 16384 + o * 32 + (c & 31)] = f2bf(W[idx]);
}

// ---------------------------------------------------------------------------
// Stage E1: fused bilinear-upsample + hardswish + bf16 MFMA GEMM + GN stats.
// grid (56 dst rows, 32 b), 256 thr (4 waves). Block: y[512 o][56 px of row].
// v2: the two M-rows this block needs (512c x 14) are staged once into sM;
// B staging interpolates from LDS instead of scalar global loads.
// ---------------------------------------------------------------------------
__global__ __launch_bounds__(256) void k_gemm_stats(
    const unsigned short* __restrict__ Ws,
    const float* __restrict__ M,
    unsigned short* __restrict__ Y,
    float* __restrict__ stats)
{
    int row = blockIdx.x;
    int b = blockIdx.y;
    int t = threadIdx.x;
    __shared__ __attribute__((aligned(16))) unsigned short lA[512 * 40]; // [o][32c] pad 40
    __shared__ __attribute__((aligned(16))) unsigned short lB[64 * 40];  // [px][32c] pad 40
    __shared__ float sM[512 * 15];   // [c][0..6]=row y0, [7..13]=row y1, pad 15
    __shared__ int six0[64], six1[64];
    __shared__ float sfx[64];

    float srcy = row * 0.125f - 0.4375f;
    int iy0 = (int)floorf(srcy);
    float fy = srcy - (float)iy0;
    int y0 = min(max(iy0, 0), 6);
    int y1 = min(max(iy0 + 1, 0), 6);

    const float* Mb = M + b * 512 * 49;

    if (t < 64) {
        if (t < 56) {
            float sx = t * 0.125f - 0.4375f;
            int ix0 = (int)floorf(sx);
            sfx[t] = sx - (float)ix0;
            six0[t] = min(max(ix0, 0), 6);
            six1[t] = min(max(ix0 + 1, 0), 6);
        } else { sfx[t] = 0.f; six0[t] = 0; six1[t] = 0; }
    }
    // stage the two source rows of M for all 512 channels
    for (int idx = t; idx < 512 * 14; idx += 256) {
        int c = idx / 14, rr = idx - c * 14;
        int srow = rr < 7 ? y0 : y1;
        int scol = rr < 7 ? rr : rr - 7;
        sM[c * 15 + rr] = Mb[c * 49 + srow * 7 + scol];
    }
    __syncthreads();

    f32x4 acc[8][4];
    const f32x4 zv = {0.f, 0.f, 0.f, 0.f};
    #pragma unroll
    for (int i = 0; i < 8; i++)
        #pragma unroll
        for (int j = 0; j < 4; j++) acc[i][j] = zv;

    int wv_ = t >> 6, lane = t & 63, quad = lane >> 4, l15 = lane & 15;

    for (int kk = 0; kk < 16; kk++) {
        // ---- A staging: Ws chunk kk -> lA (512x32, padded rows)
        const unsigned short* wsrc = Ws + kk * 16384;
        #pragma unroll
        for (int it = 0; it < 8; it++) {
            int u = it * 256 + t;
            int o = u >> 2, seg = u & 3;
            uint4 val = *(const uint4*)(wsrc + u * 8);
            *(uint4*)&lA[o * 40 + seg * 8] = val;
        }
        // ---- B staging: act = hardswish(bilinear(sM)) for 32 c x 64 px
        #pragma unroll
        for (int ip = 0; ip < 4; ip++) {
            int pair = ip * 256 + t;
            int px = pair >> 4, cp = pair & 15;
            int c = kk * 32 + cp * 2;
            float a0 = 0.f, a1 = 0.f;
            if (px < 56) {
                const float* m0 = sM + c * 15;
                int x0 = six0[px], x1 = six1[px];
                float fx = sfx[px];
                {
                    float r0 = m0[x0] + fx * (m0[x1] - m0[x0]);
                    float r1 = m0[7 + x0] + fx * (m0[7 + x1] - m0[7 + x0]);
                    float x = r0 + fy * (r1 - r0);
                    a0 = x * fminf(fmaxf(x + 3.f, 0.f), 6.f) * (1.f / 6.f);
                }
                const float* m1 = m0 + 15;
                {
                    float r0 = m1[x0] + fx * (m1[x1] - m1[x0]);
                    float r1 = m1[7 + x0] + fx * (m1[7 + x1] - m1[7 + x0]);
                    float x = r0 + fy * (r1 - r0);
                    a1 = x * fminf(fmaxf(x + 3.f, 0.f), 6.f) * (1.f / 6.f);
                }
            }
            unsigned int packed = (unsigned int)f2bf(a0) | ((unsigned int)f2bf(a1) << 16);
            *(unsigned int*)&lB[px * 40 + cp * 2] = packed;
        }
        __syncthreads();
        // ---- MFMA
        short8 bfr[4];
        #pragma unroll
        for (int nb = 0; nb < 4; nb++)
            bfr[nb] = *(const short8*)&lB[(nb * 16 + l15) * 40 + quad * 8];
        #pragma unroll
        for (int mb = 0; mb < 8; mb++) {
            short8 af = *(const short8*)&lA[(wv_ * 128 + mb * 16 + l15) * 40 + quad * 8];
            #pragma unroll
            for (int nb = 0; nb < 4; nb++)
                acc[mb][nb] = __builtin_amdgcn_mfma_f32_16x16x32_bf16(af, bfr[nb], acc[mb][nb], 0, 0, 0);
        }
        __syncthreads();
    }

    // ---- GN partial stats (group = 16 consecutive o = one m-block)
    #pragma unroll
    for (int mb = 0; mb < 8; mb++) {
        float s = 0.f, s2 = 0.f;
        #pragma unroll
        for (int nb = 0; nb < 4; nb++) {
            int px = nb * 16 + l15;
            if (px < 56) {
                #pragma unroll
                for (int i = 0; i < 4; i++) { float v = acc[mb][nb][i]; s += v; s2 += v * v; }
            }
        }
        s = wred_sum(s); s2 = wred_sum(s2);
        if (lane == 0) {
            int g = wv_ * 8 + mb;
            atomicAdd(&stats[(b * 32 + g) * 2], s);
            atomicAdd(&stats[(b * 32 + g) * 2 + 1], s2);
        }
    }
    // ---- store y (bf16), layout [b][row][o][56]
    unsigned short* yb = Y + (size_t)((b * 56 + row) * 512) * 56;
    #pragma unroll
    for (int mb = 0; mb < 8; mb++) {
        #pragma unroll
        for (int nb = 0; nb < 4; nb++) {
            int px = nb * 16 + l15;
            if (px < 56) {
                #pragma unroll
                for (int i = 0; i < 4; i++) {
                    int o = wv_ * 128 + mb * 16 + quad * 4 + i;
                    yb[o * 56 + px] = f2bf(acc[mb][nb][i]);
                }
            }
        }
    }
}

// ---------------------------------------------------------------------------
// Stage E1.5: finalize GN stats -> mean, rstd per (b, group)
// ---------------------------------------------------------------------------
__global__ __launch_bounds__(1024) void k_finstats(const float* __restrict__ stats,
                                                   float* __restrict__ mr)
{
    int t = threadIdx.x;  // 1024 = 32 b * 32 g
    float s = stats[t * 2], s2 = stats[t * 2 + 1];
    float m = s * (1.f / 50176.f);
    float var = s2 * (1.f / 50176.f) - m * m;
    mr[t * 2] = m;
    mr[t * 2 + 1] = rsqrtf(var + GEPS);
}

// ---------------------------------------------------------------------------
// Stage E2: normalize y, apply out_g/out_b, write fp32 output [32,512,56,56]
// grid (56 rows, 32 b), 256 thr.
// ---------------------------------------------------------------------------
__global__ __launch_bounds__(256) void k_norm_out(
    const unsigned short* __restrict__ Y, const float* __restrict__ mr,
    const float* __restrict__ og, const float* __restrict__ ob,
    float* __restrict__ out)
{
    int row = blockIdx.x, b = blockIdx.y;
    int t = threadIdx.x;
    const unsigned short* yb = Y + (size_t)((b * 56 + row) * 512) * 56;
    for (int idx2 = t; idx2 < 512 * 28; idx2 += 256) {
        int o = idx2 / 28, pp = (idx2 - o * 28) * 2;
        unsigned int u = *(const unsigned int*)(yb + o * 56 + pp);
        float v0 = bf2f((unsigned short)(u & 0xffffu));
        float v1 = bf2f((unsigned short)(u >> 16));
        int g = o >> 4;
        float m = mr[(b * 32 + g) * 2], r = mr[(b * 32 + g) * 2 + 1];
        float sc = og[o] * r;
        float sh = ob[o] - m * sc;
        float2 res = make_float2(v0 * sc + sh, v1 * sc + sh);
        *(float2*)(out + (size_t)((b * 512 + o) * 56 + row) * 56 + pp) = res;
    }
}

// ---------------------------------------------------------------------------
extern "C" void kernel_launch(void* const* d_in, const int* in_sizes, int n_in,
                              void* d_out, int out_size, void* d_ws, size_t ws_size,
                              hipStream_t stream)
{
    const float* query = (const float*)d_in[0];
    const float* key   = (const float*)d_in[1];
    const float* value = (const float*)d_in[2];
    const float* qs_w = (const float*)d_in[3];
    const float* qs_b = (const float*)d_in[4];
    const float* qs_g = (const float*)d_in[5];
    const float* qs_bb = (const float*)d_in[6];
    const float* ks_w = (const float*)d_in[7];
    const float* ks_b = (const float*)d_in[8];
    const float* ks_g = (const float*)d_in[9];
    const float* ks_bb = (const float*)d_in[10];
    const float* vs_w = (const float*)d_in[11];
    const float* vs_b = (const float*)d_in[12];
    const float* vs_g = (const float*)d_in[13];
    const float* vs_bb = (const float*)d_in[14];
    const float* wq = (const float*)d_in[15];
    const float* gq_g = (const float*)d_in[16];
    const float* gq_b = (const float*)d_in[17];
    const float* wk = (const float*)d_in[18];
    const float* gk_g = (const float*)d_in[19];
    const float* gk_b = (const float*)d_in[20];
    const float* wv = (const float*)d_in[21];
    const float* gv_g = (const float*)d_in[22];
    const float* gv_b = (const float*)d_in[23];
    const float* loc_w = (const float*)d_in[24];
    const float* loc_g = (const float*)d_in[25];
    const float* loc_b = (const float*)d_in[26];
    const float* th1_w = (const float*)d_in[27];
    const float* th2_w = (const float*)d_in[28];
    const float* logit_scale = (const float*)d_in[29];
    const float* attn_bias = (const float*)d_in[30];
    const int*   bias_idx = (const int*)d_in[31];
    const float* out_w = (const float*)d_in[32];
    const float* out_g = (const float*)d_in[33];
    const float* out_b = (const float*)d_in[34];

    char* ws = (char*)d_ws;
    size_t off = 0;
    unsigned short* Y = (unsigned short*)(ws + off); off += 102760448ULL;  // [32][56][512][56] bf16
    float* q4   = (float*)(ws + off); off += 3211264;
    float* k4   = (float*)(ws + off); off += 3211264;
    float* v4   = (float*)(ws + off); off += 3211264;
    float* qnf  = (float*)(ws + off); off += 3211264;
    float* knf  = (float*)(ws + off); off += 3211264;
    float* vf   = (float*)(ws + off); off += 3211264;
    float* Msm  = (float*)(ws + off); off += 3211264;
    float* vloc = (float*)(ws + off); off += 3211264;
    unsigned short* Wst = (unsigned short*)(ws + off); off += 524288;
    float* stats = (float*)(ws + off); off += 8192;
    float* mr    = (float*)(ws + off); off += 8192;

    hipMemsetAsync(stats, 0, 8192, stream);

    k_dwconv_bn<<<dim3(16384, 3), 256, 0, stream>>>(
        query, key, value,
        qs_w, qs_b, qs_g, qs_bb,
        ks_w, ks_b, ks_g, ks_bb,
        vs_w, vs_b, vs_g, vs_bb,
        q4, k4, v4);

    k_pw_gn<<<dim3(256, 3), 256, 0, stream>>>(
        q4, k4, v4, wq, wk, wv,
        gq_g, gq_b, gk_g, gk_b, gv_g, gv_b,
        qnf, knf, vf);

    k_vlocal<<<dim3(256), 256, 0, stream>>>(vf, loc_w, loc_g, loc_b, vloc);

    k_attn<<<dim3(49, 32), 64, 0, stream>>>(
        qnf, knf, vf, vloc, th1_w, th2_w, logit_scale, attn_bias, bias_idx, Msm);

    k_wconv<<<dim3(1024), 256, 0, stream>>>(out_w, Wst);

    k_gemm_stats<<<dim3(56, 32), 256, 0, stream>>>(Wst, Msm, Y, stats);

    k_finstats<<<dim3(1), 1024, 0, stream>>>(stats, mr);

    k_norm_out<<<dim3(56, 32), 256, 0, stream>>>(Y, mr, out_g, out_b, (float*)d_out);
}